// Round 3
// baseline (177.782 us; speedup 1.0000x reference)
//
#include <hip/hip_runtime.h>
#include <hip/hip_bf16.h>

namespace {
constexpr int NODES = 100000;
constexpr int EMBD  = 128;
constexpr int BATCH = 1024;
constexpr int NPASS = 8;      // 1024 rows / (4 waves * 32 rows)
}

typedef __attribute__((ext_vector_type(8))) short bf16x8_t;
typedef __attribute__((ext_vector_type(4))) float f32x4_t;

__device__ __forceinline__ short f2bf(float f) {
    __hip_bfloat16 h = __float2bfloat16(f);
    short s; __builtin_memcpy(&s, &h, 2); return s;
}

// combined[b][k] = emb[subj[b]][k] * rels[rel[b]][k], bf16 (A matrix, 256 KB)
__global__ void combine_kernel(const int* __restrict__ subj,
                               const int* __restrict__ rel,
                               const float* __restrict__ emb,
                               const float* __restrict__ rels,
                               short* __restrict__ out) {
    const int b = blockIdx.x;
    const int t = threadIdx.x;
    const float v = emb[(size_t)subj[b] * EMBD + t] * rels[rel[b] * EMBD + t];
    out[b * EMBD + t] = f2bf(v);
}

// C[m][n] = sum_k A[m][k]*B[n][k].
// Block = one 32-col node strip (n0 = blockIdx.x*32), held in registers (bf16,
// converted from fp32 once). 4 waves sweep all 1024 batch rows in 8 passes
// (wave w, pass p -> rows p*128 + w*32 .. +32). A is 256 KB, L2-resident,
// double-buffered across passes. Swapped-operand MFMA -> f32x4 stores along N.
__global__ __launch_bounds__(256) void distmult_kernel(
        const short* __restrict__ A,
        const float* __restrict__ B,
        float* __restrict__ C) {
    const int n0  = blockIdx.x * 32;       // 0..3124 strips
    const int tid = (int)threadIdx.x;
    const int w   = tid >> 6;
    const int l   = tid & 63;
    const int fr  = l & 15;
    const int fq  = l >> 4;

    // ---- B strip: load fp32 once, convert to bf16 MFMA A-operand fragments.
    // Fragment layout (operand row = node): row fr, k = kk*32 + fq*8 .. +8
    bf16x8_t b[2][4];
#pragma unroll
    for (int ni = 0; ni < 2; ++ni) {
        const float* p = B + (size_t)(n0 + ni * 16 + fr) * EMBD + fq * 8;
#pragma unroll
        for (int kk = 0; kk < 4; ++kk) {
            f32x4_t lo = *reinterpret_cast<const f32x4_t*>(p + kk * 32);
            f32x4_t hi = *reinterpret_cast<const f32x4_t*>(p + kk * 32 + 4);
            bf16x8_t t;
#pragma unroll
            for (int j = 0; j < 4; ++j) { t[j] = f2bf(lo[j]); t[4 + j] = f2bf(hi[j]); }
            b[ni][kk] = t;
        }
    }

    // ---- A fragments, double-buffered across passes (L2-resident source).
    bf16x8_t a[2][2][4];
    auto loadA = [&](int p, bf16x8_t (&buf)[2][4]) {
        const int m0 = p * 128 + w * 32;
#pragma unroll
        for (int mi = 0; mi < 2; ++mi) {
            const short* q = A + (m0 + mi * 16 + fr) * EMBD + fq * 8;
#pragma unroll
            for (int kk = 0; kk < 4; ++kk)
                buf[mi][kk] = *reinterpret_cast<const bf16x8_t*>(q + kk * 32);
        }
    };
    loadA(0, a[0]);

#pragma unroll
    for (int p = 0; p < NPASS; ++p) {
        if (p + 1 < NPASS) loadA(p + 1, a[(p + 1) & 1]);   // p compile-time (unrolled)

        f32x4_t acc[2][2] = {};
#pragma unroll
        for (int kk = 0; kk < 4; ++kk)
#pragma unroll
            for (int mi = 0; mi < 2; ++mi)
#pragma unroll
                for (int ni = 0; ni < 2; ++ni)
                    acc[mi][ni] = __builtin_amdgcn_mfma_f32_16x16x32_bf16(
                        b[ni][kk], a[p & 1][mi][kk], acc[mi][ni], 0, 0, 0);

        // D layout (swapped): col(lane&15)=m fragment row, row(fq*4+reg)=n
        const int m0 = p * 128 + w * 32;
#pragma unroll
        for (int mi = 0; mi < 2; ++mi) {
            const size_t rowoff = (size_t)(m0 + mi * 16 + fr) * NODES;
#pragma unroll
            for (int ni = 0; ni < 2; ++ni)
                *reinterpret_cast<f32x4_t*>(C + rowoff + n0 + ni * 16 + fq * 4) =
                    acc[mi][ni];
        }
    }
}

extern "C" void kernel_launch(void* const* d_in, const int* in_sizes, int n_in,
                              void* d_out, int out_size, void* d_ws, size_t ws_size,
                              hipStream_t stream) {
    const int*   subj = (const int*)d_in[0];
    const int*   rel  = (const int*)d_in[1];
    const float* emb  = (const float*)d_in[2];
    const float* rels = (const float*)d_in[3];
    float* out = (float*)d_out;
    short* combined = (short*)d_ws;   // 256 KB

    combine_kernel<<<BATCH, EMBD, 0, stream>>>(subj, rel, emb, rels, combined);
    distmult_kernel<<<NODES / 32, 256, 0, stream>>>(combined, emb, out);
}

// Round 4
// 167.179 us; speedup vs baseline: 1.0634x; 1.0634x over previous
//
#include <hip/hip_runtime.h>
#include <hip/hip_bf16.h>

namespace {
constexpr int NODES = 100000;
constexpr int EMBD  = 128;
constexpr int BATCH = 1024;
constexpr int STRIP = 80;     // node cols per block (100000/80 = 1250 blocks)
constexpr int NI    = 5;      // 16-col MFMA tiles per strip
constexpr int NPASS = 8;      // 1024 rows / (4 waves * 32 rows)
}

typedef __attribute__((ext_vector_type(8))) short bf16x8_t;
typedef __attribute__((ext_vector_type(4))) float f32x4_t;

__device__ __forceinline__ short f2bf(float f) {
    __hip_bfloat16 h = __float2bfloat16(f);
    short s; __builtin_memcpy(&s, &h, 2); return s;
}

// combined[b][k] = emb[subj[b]][k] * rels[rel[b]][k], bf16 (A matrix, 256 KB)
__global__ void combine_kernel(const int* __restrict__ subj,
                               const int* __restrict__ rel,
                               const float* __restrict__ emb,
                               const float* __restrict__ rels,
                               short* __restrict__ out) {
    const int b = blockIdx.x;
    const int t = threadIdx.x;
    const float v = emb[(size_t)subj[b] * EMBD + t] * rels[rel[b] * EMBD + t];
    out[b * EMBD + t] = f2bf(v);
}

// C[m][n] = sum_k A[m][k]*B[n][k]
// Block = 80-col node strip x all 1024 batch rows. Each wave keeps the whole
// 80x128 B strip in registers (bf16, converted from fp32 once); 4 waves sweep
// 1024 rows in 8 passes of 32 rows each (wave w, pass p -> rows p*128+w*32).
// A (256 KB bf16) is L2-resident, double-buffered across passes.
// Swapped-operand MFMA: acc = mfma(b_frag, a_frag) ->
//   D col(lane&15) = batch row fragment, D row(fq*4+reg) = node -> f32x4 along N.
__global__ __launch_bounds__(256, 2) void distmult_kernel(
        const short* __restrict__ A,
        const float* __restrict__ B,
        float* __restrict__ C) {
    const int n0  = blockIdx.x * STRIP;
    const int tid = (int)threadIdx.x;
    const int w   = tid >> 6;
    const int l   = tid & 63;
    const int fr  = l & 15;
    const int fq  = l >> 4;

    // ---- B strip -> registers (80 VGPRs), fp32 read once, cvt to bf16.
    bf16x8_t b[NI][4];
#pragma unroll
    for (int ni = 0; ni < NI; ++ni) {
        const float* p = B + (size_t)(n0 + ni * 16 + fr) * EMBD + fq * 8;
#pragma unroll
        for (int kk = 0; kk < 4; ++kk) {
            f32x4_t lo = *reinterpret_cast<const f32x4_t*>(p + kk * 32);
            f32x4_t hi = *reinterpret_cast<const f32x4_t*>(p + kk * 32 + 4);
            bf16x8_t t;
#pragma unroll
            for (int j = 0; j < 4; ++j) { t[j] = f2bf(lo[j]); t[4 + j] = f2bf(hi[j]); }
            b[ni][kk] = t;
        }
    }

    // ---- A fragments, double-buffered across passes (L2-resident source).
    bf16x8_t a[2][2][4];
    auto loadA = [&](int p, bf16x8_t (&buf)[2][4]) {
        const int m0 = p * 128 + w * 32;
#pragma unroll
        for (int mi = 0; mi < 2; ++mi) {
            const short* q = A + (m0 + mi * 16 + fr) * EMBD + fq * 8;
#pragma unroll
            for (int kk = 0; kk < 4; ++kk)
                buf[mi][kk] = *reinterpret_cast<const bf16x8_t*>(q + kk * 32);
        }
    };
    loadA(0, a[0]);

#pragma unroll
    for (int p = 0; p < NPASS; ++p) {
        if (p + 1 < NPASS) loadA(p + 1, a[(p + 1) & 1]);   // p is compile-time

        f32x4_t acc[2][NI] = {};
#pragma unroll
        for (int kk = 0; kk < 4; ++kk)
#pragma unroll
            for (int mi = 0; mi < 2; ++mi)
#pragma unroll
                for (int ni = 0; ni < NI; ++ni)
                    acc[mi][ni] = __builtin_amdgcn_mfma_f32_16x16x32_bf16(
                        b[ni][kk], a[p & 1][mi][kk], acc[mi][ni], 0, 0, 0);

        const int m0 = p * 128 + w * 32;
#pragma unroll
        for (int mi = 0; mi < 2; ++mi) {
            const size_t rowoff = (size_t)(m0 + mi * 16 + fr) * NODES;
#pragma unroll
            for (int ni = 0; ni < NI; ++ni)
                *reinterpret_cast<f32x4_t*>(C + rowoff + n0 + ni * 16 + fq * 4) =
                    acc[mi][ni];
        }
    }
}

extern "C" void kernel_launch(void* const* d_in, const int* in_sizes, int n_in,
                              void* d_out, int out_size, void* d_ws, size_t ws_size,
                              hipStream_t stream) {
    const int*   subj = (const int*)d_in[0];
    const int*   rel  = (const int*)d_in[1];
    const float* emb  = (const float*)d_in[2];
    const float* rels = (const float*)d_in[3];
    float* out = (float*)d_out;
    short* combined = (short*)d_ws;   // 256 KB

    combine_kernel<<<BATCH, EMBD, 0, stream>>>(subj, rel, emb, rels, combined);
    distmult_kernel<<<NODES / STRIP, 256, 0, stream>>>(combined, emb, out);
}

// Round 5
// 112.753 us; speedup vs baseline: 1.5767x; 1.4827x over previous
//
#include <hip/hip_runtime.h>
#include <hip/hip_bf16.h>

namespace {
constexpr int NODES = 100000;
constexpr int EMBD  = 128;
constexpr int BATCH = 1024;
constexpr int STRIP = 160;    // 160 cols * 4 B = 640 B/row = 5 full 128B lines
constexpr int NI    = 10;     // 16-col MFMA tiles per strip
constexpr int NPASS = 8;      // 1024 rows / (4 waves * 32 rows)
}

typedef __attribute__((ext_vector_type(8))) short bf16x8_t;
typedef __attribute__((ext_vector_type(4))) float f32x4_t;

__device__ __forceinline__ short f2bf(float f) {
    __hip_bfloat16 h = __float2bfloat16(f);
    short s; __builtin_memcpy(&s, &h, 2); return s;
}

// combined[b][k] = emb[subj[b]][k] * rels[rel[b]][k], bf16 (A matrix, 256 KB)
__global__ void combine_kernel(const int* __restrict__ subj,
                               const int* __restrict__ rel,
                               const float* __restrict__ emb,
                               const float* __restrict__ rels,
                               short* __restrict__ out) {
    const int b = blockIdx.x;
    const int t = threadIdx.x;
    const float v = emb[(size_t)subj[b] * EMBD + t] * rels[rel[b] * EMBD + t];
    out[b * EMBD + t] = f2bf(v);
}

// C[m][n] = sum_k A[m][k]*B[n][k]
// Block = 160-col node strip x all 1024 batch rows, 4 waves.
// B strip: fp32 read ONCE (coalesced), cvt->bf16, staged in 40 KB LDS with
// XOR swizzle (byte ^= (row&7)<<4) -> conflict-free ds_read_b128 fragments.
// After one barrier the pass loop is barrier-free (LDS read-only).
// Waves sweep 1024 rows in 8 passes of 128 (wave w -> rows p*128+w*32..+32).
// Swapped-operand MFMA: D col(lane&15)=batch row, D row(fq*4+reg)=node
//   -> f32x4 stores along N; block chunk per row = 640 B, line-aligned.
__global__ __launch_bounds__(256, 3) void distmult_kernel(
        const short* __restrict__ A,
        const float* __restrict__ B,
        float* __restrict__ C) {
    __shared__ short Bs[STRIP * EMBD];     // 40 KB
    const int n0  = blockIdx.x * STRIP;
    const int tid = (int)threadIdx.x;

    // ---- stage B strip: 20480 bf16 elems, 80 per thread (10 chunks of 8)
#pragma unroll
    for (int c = 0; c < 10; ++c) {
        const int e = (c * 256 + tid) * 8;       // flat elem index
        const int r = e >> 7;                    // node row in strip
        const int k = e & 127;                   // k col (multiple of 8)
        const float* p = B + (size_t)(n0 + r) * EMBD + k;
        f32x4_t lo = *reinterpret_cast<const f32x4_t*>(p);
        f32x4_t hi = *reinterpret_cast<const f32x4_t*>(p + 4);
        bf16x8_t v;
#pragma unroll
        for (int j = 0; j < 4; ++j) { v[j] = f2bf(lo[j]); v[4 + j] = f2bf(hi[j]); }
        const int byteaddr = r * 256 + ((k * 2) ^ ((r & 7) << 4));
        *reinterpret_cast<bf16x8_t*>(reinterpret_cast<char*>(Bs) + byteaddr) = v;
    }
    __syncthreads();

    const int w  = tid >> 6;
    const int l  = tid & 63;
    const int fr = l & 15;
    const int fq = l >> 4;
    const int swz = (fr & 7) << 4;               // lane's XOR key (row&7 == fr&7)

    // per-lane LDS base for fragment rows: row = ni*16 + fr
    const char* BsBase = reinterpret_cast<const char*>(Bs) + fr * 256;

    // A fragments for current pass (L2-hot source; pass loop unrolled ->
    // compiler pipelines these loads across passes)
#pragma unroll
    for (int p = 0; p < NPASS; ++p) {
        const int m0 = p * 128 + w * 32;
        bf16x8_t a[2][4];
#pragma unroll
        for (int mi = 0; mi < 2; ++mi) {
            const short* q = A + (m0 + mi * 16 + fr) * EMBD + fq * 8;
#pragma unroll
            for (int kk = 0; kk < 4; ++kk)
                a[mi][kk] = *reinterpret_cast<const bf16x8_t*>(q + kk * 32);
        }

        f32x4_t acc[2][NI] = {};
#pragma unroll
        for (int kk = 0; kk < 4; ++kk) {
#pragma unroll
            for (int h = 0; h < 2; ++h) {        // split NI to cap live B regs
                bf16x8_t bfr[5];
#pragma unroll
                for (int j = 0; j < 5; ++j) {
                    const int ni = h * 5 + j;
                    const int byteoff = ni * 4096 + ((kk * 64 + fq * 16) ^ swz);
                    bfr[j] = *reinterpret_cast<const bf16x8_t*>(BsBase + byteoff);
                }
#pragma unroll
                for (int mi = 0; mi < 2; ++mi)
#pragma unroll
                    for (int j = 0; j < 5; ++j)
                        acc[mi][h * 5 + j] = __builtin_amdgcn_mfma_f32_16x16x32_bf16(
                            bfr[j], a[mi][kk], acc[mi][h * 5 + j], 0, 0, 0);
            }
        }

#pragma unroll
        for (int mi = 0; mi < 2; ++mi) {
            const size_t rowoff = (size_t)(m0 + mi * 16 + fr) * NODES;
#pragma unroll
            for (int ni = 0; ni < NI; ++ni)
                *reinterpret_cast<f32x4_t*>(C + rowoff + n0 + ni * 16 + fq * 4) =
                    acc[mi][ni];
        }
    }
}

extern "C" void kernel_launch(void* const* d_in, const int* in_sizes, int n_in,
                              void* d_out, int out_size, void* d_ws, size_t ws_size,
                              hipStream_t stream) {
    const int*   subj = (const int*)d_in[0];
    const int*   rel  = (const int*)d_in[1];
    const float* emb  = (const float*)d_in[2];
    const float* rels = (const float*)d_in[3];
    float* out = (float*)d_out;
    short* combined = (short*)d_ws;   // 256 KB

    combine_kernel<<<BATCH, EMBD, 0, stream>>>(subj, rel, emb, rels, combined);
    distmult_kernel<<<NODES / STRIP, 256, 0, stream>>>(combined, emb, out);
}